// Round 12
// baseline (93.558 us; speedup 1.0000x reference)
//
#include <hip/hip_runtime.h>
#include <math.h>

#define T_FRAMES 1025
#define TSTRIDE  1032          // row stride for Ht; 1032*8 = 129*64 -> rows 64B-aligned
#define BATCH    4
#define LWAV     131072
#define KWC      1023
#define MFFT     2048
#define PI_F     3.14159265358979323846f

struct c32 { float r, i; };
__device__ __forceinline__ c32 mkc(float r, float i){ c32 z; z.r=r; z.i=i; return z; }
__device__ __forceinline__ c32 cadd(c32 a, c32 b){ return mkc(a.r+b.r, a.i+b.i); }
__device__ __forceinline__ c32 csub(c32 a, c32 b){ return mkc(a.r-b.r, a.i-b.i); }
__device__ __forceinline__ c32 cmul(c32 a, c32 b){ return mkc(a.r*b.r - a.i*b.i, a.r*b.i + a.i*b.r); }
__device__ __forceinline__ c32 cni(c32 a){ return mkc(a.i, -a.r); }           // a * (-i)
#define C8F 0.70710678118654752440f
__device__ __forceinline__ c32 c8p(c32 a){ return mkc(C8F*(a.r+a.i), C8F*(a.i-a.r)); }   // * e^{-i pi/4}
__device__ __forceinline__ c32 c8m(c32 a){ return mkc(C8F*(a.i-a.r), -C8F*(a.r+a.i)); }  // * e^{-i 3pi/4}

__device__ __forceinline__ int pX(int j){ return j + (j >> 5); }
__device__ __forceinline__ int pS(int j){ return j + (j >> 3); }
__device__ __forceinline__ int pP(int j){ return j + (j >> 3); }   // conv radix-4 pad (per-8)
__device__ __forceinline__ int rev9(int j){ return (int)(__brev((unsigned)j) >> 23); }

// e^{-2*pi*i*r/2048} via fast HW sincos
__device__ __forceinline__ c32 wexp(int r) {
    float s, c;
    __sincosf((float)r * (-PI_F / 1024.0f), &s, &c);
    return mkc(c, s);
}

// ---- radix-8 DIF step (stft/afft); w3 = W^{pos} of current level
__device__ __forceinline__ void dif8_tw(c32 y[8], c32 w3) {
    c32 w2 = cmul(w3, w3), w1 = cmul(w2, w2);
    c32 u[8], v[8], d;
    d = csub(y[0], y[4]); u[0] = cadd(y[0], y[4]); u[4] = cmul(d, w3);
    d = csub(y[1], y[5]); u[1] = cadd(y[1], y[5]); u[5] = c8p(cmul(d, w3));
    d = csub(y[2], y[6]); u[2] = cadd(y[2], y[6]); u[6] = cni(cmul(d, w3));
    d = csub(y[3], y[7]); u[3] = cadd(y[3], y[7]); u[7] = c8m(cmul(d, w3));
    d = csub(u[0], u[2]); v[0] = cadd(u[0], u[2]); v[2] = cmul(d, w2);
    d = csub(u[1], u[3]); v[1] = cadd(u[1], u[3]); v[3] = cni(cmul(d, w2));
    d = csub(u[4], u[6]); v[4] = cadd(u[4], u[6]); v[6] = cmul(d, w2);
    d = csub(u[5], u[7]); v[5] = cadd(u[5], u[7]); v[7] = cni(cmul(d, w2));
    d = csub(v[0], v[1]); y[0] = cadd(v[0], v[1]); y[1] = cmul(d, w1);
    d = csub(v[2], v[3]); y[2] = cadd(v[2], v[3]); y[3] = cmul(d, w1);
    d = csub(v[4], v[5]); y[4] = cadd(v[4], v[5]); y[5] = cmul(d, w1);
    d = csub(v[6], v[7]); y[6] = cadd(v[6], v[7]); y[7] = cmul(d, w1);
}
__device__ __forceinline__ void dif8_nt(c32 y[8]) {
    c32 u[8], v[8], d;
    d = csub(y[0], y[4]); u[0] = cadd(y[0], y[4]); u[4] = d;
    d = csub(y[1], y[5]); u[1] = cadd(y[1], y[5]); u[5] = c8p(d);
    d = csub(y[2], y[6]); u[2] = cadd(y[2], y[6]); u[6] = cni(d);
    d = csub(y[3], y[7]); u[3] = cadd(y[3], y[7]); u[7] = c8m(d);
    d = csub(u[0], u[2]); v[0] = cadd(u[0], u[2]); v[2] = d;
    d = csub(u[1], u[3]); v[1] = cadd(u[1], u[3]); v[3] = cni(d);
    d = csub(u[4], u[6]); v[4] = cadd(u[4], u[6]); v[6] = d;
    d = csub(u[5], u[7]); v[5] = cadd(u[5], u[7]); v[7] = cni(d);
    d = csub(v[0], v[1]); y[0] = cadd(v[0], v[1]); y[1] = d;
    d = csub(v[2], v[3]); y[2] = cadd(v[2], v[3]); y[3] = d;
    d = csub(v[4], v[5]); y[4] = cadd(v[4], v[5]); y[5] = d;
    d = csub(v[6], v[7]); y[6] = cadd(v[6], v[7]); y[7] = d;
}
// ---- radix-4 DIF step (conv): elements at pos + k*m, w = W_{4m}^{pos}
// composition of two standard radix-2 DIF stages -> standard bitrev placement:
// g0 = t0+t1 ; g1 = (t0-t1)w^2 ; g2 = (t2+t3)w ; g3 = (t2-t3)w^3
__device__ __forceinline__ void dif4_tw(c32 y[4], c32 w) {
    c32 w2 = cmul(w, w), w3 = cmul(w2, w);
    c32 t0 = cadd(y[0], y[2]), t1 = cadd(y[1], y[3]);
    c32 t2 = csub(y[0], y[2]), t3 = cni(csub(y[1], y[3]));
    y[0] = cadd(t0, t1);
    y[1] = cmul(csub(t0, t1), w2);
    y[2] = cmul(cadd(t2, t3), w);
    y[3] = cmul(csub(t2, t3), w3);
}
// ---- radix-4 DIT step: elements at pos + k*m in block of 4m, w = W_{4m}^{pos}
__device__ __forceinline__ void dit4(c32 y[4], c32 w) {
    c32 w2 = cmul(w, w);
    c32 t1 = cmul(y[1], w2); c32 u0 = cadd(y[0], t1), u1 = csub(y[0], t1);
    c32 t3 = cmul(y[3], w2); c32 u2 = cadd(y[2], t3), u3 = csub(y[2], t3);
    c32 s2 = cmul(u2, w);      y[0] = cadd(u0, s2); y[2] = csub(u0, s2);
    c32 s3 = cni(cmul(u3, w)); y[1] = cadd(u1, s3); y[3] = csub(u1, s3);
}
__device__ __forceinline__ void dif4(c32 y[4]) {       // w = 1 (final DIF stage pair)
    c32 u0 = cadd(y[0], y[2]), d0 = csub(y[0], y[2]);
    c32 u1 = cadd(y[1], y[3]), d1 = cni(csub(y[1], y[3]));
    y[0] = cadd(u0, u1); y[1] = csub(u0, u1);
    y[2] = cadd(d0, d1); y[3] = csub(d0, d1);
}

// ---------------- stage1: blocks 0..1027 = STFT (4 frames/block, 1 per wave);
// 1028..1034 = alpha-FFT; 1035 zeroes out.
__global__ __launch_bounds__(256) void stage1_kernel(const float* __restrict__ wave,
                                                     const float* __restrict__ win,
                                                     const float* __restrict__ ar,
                                                     const float* __restrict__ ai,
                                                     float2* __restrict__ Ht,
                                                     float2* __restrict__ Afbr,
                                                     float* __restrict__ out) {
    __shared__ float lds[4608];      // stft: Fr[4][576] | Fi[4][576]; afft: Xr[2112] | Xi[2112]
    const int tid = threadIdx.x;

    if (blockIdx.x < 1028) {
        float* Fr = lds;             // [4][576] flattened
        float* Fi = lds + 2304;
        const int w = tid >> 6, l = tid & 63;
        const int b = blockIdx.x / 257;
        const int t0 = (blockIdx.x - b * 257) << 2;
        const int t = t0 + w;
        const float* wb = wave + (size_t)b * LWAV;

        if (t < T_FRAMES) {
            c32 y[8];
#pragma unroll
            for (int k = 0; k < 8; ++k) {
                int s = l + (k << 6);
                int posn = t * 128 + s - 256;
                int ix = posn < 0 ? -posn : (posn >= LWAV ? 2 * LWAV - 2 - posn : posn);
                y[k] = mkc(wb[ix] * win[s], 0.f);
            }
            dif8_tw(y, wexp(l << 2));
#pragma unroll
            for (int k = 0; k < 8; ++k) { int p = pS(l + (k << 6)); Fr[w*576+p] = y[k].r; Fi[w*576+p] = y[k].i; }
            __builtin_amdgcn_wave_barrier();
            {
                int base = ((l >> 3) << 6) + (l & 7);
#pragma unroll
                for (int k = 0; k < 8; ++k) { int p = pS(base + (k << 3)); y[k] = mkc(Fr[w*576+p], Fi[w*576+p]); }
                dif8_tw(y, wexp((l & 7) << 5));
#pragma unroll
                for (int k = 0; k < 8; ++k) { int p = pS(base + (k << 3)); Fr[w*576+p] = y[k].r; Fi[w*576+p] = y[k].i; }
            }
            __builtin_amdgcn_wave_barrier();
            {
#pragma unroll
                for (int k = 0; k < 8; ++k) { int p = pS((l << 3) + k); y[k] = mkc(Fr[w*576+p], Fi[w*576+p]); }
                dif8_nt(y);
#pragma unroll
                for (int k = 0; k < 8; ++k) { int p = pS((l << 3) + k); Fr[w*576+p] = y[k].r; Fi[w*576+p] = y[k].i; }
            }
        }
        __syncthreads();
        // transposed writeout: rows p = tid, tid+256 (bin <= 256 only); 4 t's per row
        const bool full = (t0 + 3 < T_FRAMES);
#pragma unroll
        for (int h = 0; h < 2; ++h) {
            int p = tid + (h << 8);
            int bin = rev9(p);
            if (bin > 256) continue;
            int ps = pS(p);
            size_t rowbase = (size_t)(b * 512 + p) * TSTRIDE + t0;
            if (full) {
                float4* dst = (float4*)(Ht + rowbase);     // 32B aligned (t0 mult of 4)
                dst[0] = make_float4(Fr[0*576+ps], Fi[0*576+ps], Fr[1*576+ps], Fi[1*576+ps]);
                dst[1] = make_float4(Fr[2*576+ps], Fi[2*576+ps], Fr[3*576+ps], Fi[3*576+ps]);
            } else {
                for (int jj = 0; jj < 4; ++jj)
                    if (t0 + jj < T_FRAMES) Ht[rowbase + jj] = make_float2(Fr[jj*576+ps], Fi[jj*576+ps]);
            }
        }
    } else if (blockIdx.x < 1035) {
        // ---- alpha FFT: Af_br[q][p] = conj(DIF2048(conj(alpha_q) zero-pad))[p]
        float* Xr = lds;
        float* Xi = lds + 2112;
        const int q = blockIdx.x - 1028;
        c32 y[8];
#pragma unroll
        for (int k = 0; k < 8; ++k) {
            int j = tid + (k << 8);
            y[k] = (j < KWC) ? mkc(ar[q * KWC + j], -ai[q * KWC + j]) : mkc(0.f, 0.f);
        }
        dif8_tw(y, wexp(tid));
#pragma unroll
        for (int k = 0; k < 8; ++k) { int p = pX(tid + (k << 8)); Xr[p] = y[k].r; Xi[p] = y[k].i; }
        __syncthreads();
        {
            int base = ((tid >> 5) << 8) + (tid & 31);
#pragma unroll
            for (int k = 0; k < 8; ++k) { int p = pX(base + (k << 5)); y[k] = mkc(Xr[p], Xi[p]); }
            dif8_tw(y, wexp((tid & 31) << 3));
#pragma unroll
            for (int k = 0; k < 8; ++k) { int p = pX(base + (k << 5)); Xr[p] = y[k].r; Xi[p] = y[k].i; }
        }
        __syncthreads();
        {
            int base = ((tid & 63) << 5) + (tid >> 6);
#pragma unroll
            for (int k = 0; k < 8; ++k) { int p = pX(base + (k << 2)); y[k] = mkc(Xr[p], Xi[p]); }
            dif8_tw(y, wexp((tid >> 6) << 6));
#pragma unroll
            for (int k = 0; k < 8; ++k) { int p = pX(base + (k << 2)); Xr[p] = y[k].r; Xi[p] = y[k].i; }
        }
        __syncthreads();
#pragma unroll
        for (int h = 0; h < 2; ++h) {
            int g = tid + (h << 8);
            c32 z4[4];
#pragma unroll
            for (int k = 0; k < 4; ++k) { int p = pX((g << 2) + k); z4[k] = mkc(Xr[p], Xi[p]); }
            dif4(z4);
#pragma unroll
            for (int k = 0; k < 4; ++k) Afbr[(q << 11) + (g << 2) + k] = make_float2(z4[k].r, -z4[k].i);
        }
    } else {
        if (tid == 0) *out = 0.f;
    }
}

// ---------------- conv: 512 threads, 1 row/block, radix-4 pipeline.
// 5 DIF4 phases -> fused [radix-2 + pointwise + radix-2] -> 5 DIT4 phases -> masked |.|^2.
// 1028 blocks x 8 waves, LDS 18.5 KB -> ~32 waves/CU.
__global__ __launch_bounds__(512) void conv_kernel(const float2* __restrict__ Ht,
                                                   const float2* __restrict__ Afbr,
                                                   float* __restrict__ out) {
    __shared__ float lds[4616];   // Xr[2304] | Xi[2304] | red[8]
    float* Xr = lds;
    float* Xi = lds + 2304;
    float* red = lds + 4608;
    const int tid = threadIdx.x;           // 0..511
    const int r = blockIdx.x;              // 0..1027
    const int b = r / 257;
    const int n = r - b * 257;             // bin 0..256
    const int pr = rev9(n);                // Ht row holding bin n

    const float2* row = Ht + (size_t)(b * 512 + pr) * TSTRIDE;
    c32 y[4];
    // F1: Ncur=2048, m=512: elements tid + 512k, w = W_2048^tid
#pragma unroll
    for (int k = 0; k < 4; ++k) {
        int j = tid + (k << 9);
        c32 v = mkc(0.f, 0.f);
        if (j < T_FRAMES) { float2 h = row[j]; v = mkc(h.x, h.y); }
        y[k] = v;
    }
    dif4_tw(y, wexp(tid));
#pragma unroll
    for (int k = 0; k < 4; ++k) { int p = pP(tid + (k << 9)); Xr[p] = y[k].r; Xi[p] = y[k].i; }
    __syncthreads();
    // F2: Ncur=512, m=128: base = 512c + pos, c = tid>>7, pos = tid&127, w = W_512^pos
    {
        int base = ((tid >> 7) << 9) + (tid & 127);
#pragma unroll
        for (int k = 0; k < 4; ++k) { int p = pP(base + (k << 7)); y[k] = mkc(Xr[p], Xi[p]); }
        dif4_tw(y, wexp((tid & 127) << 2));
#pragma unroll
        for (int k = 0; k < 4; ++k) { int p = pP(base + (k << 7)); Xr[p] = y[k].r; Xi[p] = y[k].i; }
    }
    __syncthreads();
    // F3: Ncur=128, m=32: base = 128c + pos, c = tid>>5, pos = tid&31, w = W_128^pos
    {
        int base = ((tid >> 5) << 7) + (tid & 31);
#pragma unroll
        for (int k = 0; k < 4; ++k) { int p = pP(base + (k << 5)); y[k] = mkc(Xr[p], Xi[p]); }
        dif4_tw(y, wexp((tid & 31) << 4));
#pragma unroll
        for (int k = 0; k < 4; ++k) { int p = pP(base + (k << 5)); Xr[p] = y[k].r; Xi[p] = y[k].i; }
    }
    __syncthreads();
    // F4: Ncur=32, m=8: base = 32c + pos, c = tid>>3, pos = tid&7, w = W_32^pos
    {
        int base = ((tid >> 3) << 5) + (tid & 7);
#pragma unroll
        for (int k = 0; k < 4; ++k) { int p = pP(base + (k << 3)); y[k] = mkc(Xr[p], Xi[p]); }
        dif4_tw(y, wexp((tid & 7) << 6));
#pragma unroll
        for (int k = 0; k < 4; ++k) { int p = pP(base + (k << 3)); Xr[p] = y[k].r; Xi[p] = y[k].i; }
    }
    __syncthreads();
    // F5: Ncur=8, m=2: base = 8c + pos, c = tid>>1, pos = tid&1, w = W_8^pos
    {
        int base = ((tid >> 1) << 3) + (tid & 1);
#pragma unroll
        for (int k = 0; k < 4; ++k) { int p = pP(base + (k << 1)); y[k] = mkc(Xr[p], Xi[p]); }
        dif4_tw(y, wexp((tid & 1) << 8));
#pragma unroll
        for (int k = 0; k < 4; ++k) { int p = pP(base + (k << 1)); Xr[p] = y[k].r; Xi[p] = y[k].i; }
    }
    __syncthreads();
    // FUSED: F6 radix-2 (stride 1) + pointwise + I1 radix-2 (stride 1), on 4 consecutive
    {
        c32 p1 = wexp(-(n << 2));                      // e^{+2pi i n/512}
        c32 p2 = cmul(p1, p1);
        c32 p3 = cmul(p2, p1);
        const int a0 = tid << 2;
        const int q0 = pP(a0);                         // 4 consecutive, same pad-8 group
        c32 z[4];
#pragma unroll
        for (int k = 0; k < 4; ++k) z[k] = mkc(Xr[q0 + k], Xi[q0 + k]);
        // F6: pairs (0,1),(2,3), no twiddle
        { c32 a = z[0], bq = z[1]; z[0] = cadd(a, bq); z[1] = csub(a, bq); }
        { c32 a = z[2], bq = z[3]; z[2] = cadd(a, bq); z[3] = csub(a, bq); }
        const float4* af4 = (const float4*)(Afbr + a0);
#pragma unroll
        for (int k = 0; k < 4; ++k) {
            float4 a;
            c32 Kk;
            a = af4[(3 << 10) + (k >> 1)];     // q'=0
            float ax = (k & 1) ? a.z : a.x, ay = (k & 1) ? a.w : a.y;
            Kk = mkc(ax, ay);
            a = af4[(4 << 10) + (k >> 1)]; ax = (k & 1) ? a.z : a.x; ay = (k & 1) ? a.w : a.y;
            Kk.r += p1.r * ax - p1.i * ay;  Kk.i += p1.r * ay + p1.i * ax;
            a = af4[(2 << 10) + (k >> 1)]; ax = (k & 1) ? a.z : a.x; ay = (k & 1) ? a.w : a.y;
            Kk.r += p1.r * ax + p1.i * ay;  Kk.i += p1.r * ay - p1.i * ax;
            a = af4[(5 << 10) + (k >> 1)]; ax = (k & 1) ? a.z : a.x; ay = (k & 1) ? a.w : a.y;
            Kk.r += p2.r * ax - p2.i * ay;  Kk.i += p2.r * ay + p2.i * ax;
            a = af4[(1 << 10) + (k >> 1)]; ax = (k & 1) ? a.z : a.x; ay = (k & 1) ? a.w : a.y;
            Kk.r += p2.r * ax + p2.i * ay;  Kk.i += p2.r * ay - p2.i * ax;
            a = af4[(6 << 10) + (k >> 1)]; ax = (k & 1) ? a.z : a.x; ay = (k & 1) ? a.w : a.y;
            Kk.r += p3.r * ax - p3.i * ay;  Kk.i += p3.r * ay + p3.i * ax;
            a = af4[(0 << 10) + (k >> 1)]; ax = (k & 1) ? a.z : a.x; ay = (k & 1) ? a.w : a.y;
            Kk.r += p3.r * ax + p3.i * ay;  Kk.i += p3.r * ay - p3.i * ax;
            c32 P = cmul(z[k], Kk);
            z[k] = mkc(P.r, -P.i);             // conj for inverse-via-forward
        }
        // I1: pairs (0,1),(2,3), no twiddle
        { c32 a = z[0], bq = z[1]; z[0] = cadd(a, bq); z[1] = csub(a, bq); }
        { c32 a = z[2], bq = z[3]; z[2] = cadd(a, bq); z[3] = csub(a, bq); }
#pragma unroll
        for (int k = 0; k < 4; ++k) { Xr[q0 + k] = z[k].r; Xi[q0 + k] = z[k].i; }
    }
    __syncthreads();
    // I2: block 8, m=2: base = 8c + pos, c = tid>>1, pos = tid&1, w = W_8^pos
    {
        int base = ((tid >> 1) << 3) + (tid & 1);
#pragma unroll
        for (int k = 0; k < 4; ++k) { int p = pP(base + (k << 1)); y[k] = mkc(Xr[p], Xi[p]); }
        dit4(y, wexp((tid & 1) << 8));
#pragma unroll
        for (int k = 0; k < 4; ++k) { int p = pP(base + (k << 1)); Xr[p] = y[k].r; Xi[p] = y[k].i; }
    }
    __syncthreads();
    // I3: block 32, m=8: base = 32c + pos, c = tid>>3, pos = tid&7, w = W_32^pos
    {
        int base = ((tid >> 3) << 5) + (tid & 7);
#pragma unroll
        for (int k = 0; k < 4; ++k) { int p = pP(base + (k << 3)); y[k] = mkc(Xr[p], Xi[p]); }
        dit4(y, wexp((tid & 7) << 6));
#pragma unroll
        for (int k = 0; k < 4; ++k) { int p = pP(base + (k << 3)); Xr[p] = y[k].r; Xi[p] = y[k].i; }
    }
    __syncthreads();
    // I4: block 128, m=32: base = 128c + pos, c = tid>>5, pos = tid&31, w = W_128^pos
    {
        int base = ((tid >> 5) << 7) + (tid & 31);
#pragma unroll
        for (int k = 0; k < 4; ++k) { int p = pP(base + (k << 5)); y[k] = mkc(Xr[p], Xi[p]); }
        dit4(y, wexp((tid & 31) << 4));
#pragma unroll
        for (int k = 0; k < 4; ++k) { int p = pP(base + (k << 5)); Xr[p] = y[k].r; Xi[p] = y[k].i; }
    }
    __syncthreads();
    // I5: block 512, m=128: base = 512c + pos, c = tid>>7, pos = tid&127, w = W_512^pos
    {
        int base = ((tid >> 7) << 9) + (tid & 127);
#pragma unroll
        for (int k = 0; k < 4; ++k) { int p = pP(base + (k << 7)); y[k] = mkc(Xr[p], Xi[p]); }
        dit4(y, wexp((tid & 127) << 2));
#pragma unroll
        for (int k = 0; k < 4; ++k) { int p = pP(base + (k << 7)); Xr[p] = y[k].r; Xi[p] = y[k].i; }
    }
    __syncthreads();
    // I6: block 2048, m=512: elements tid + 512k, w = W_2048^tid; masked |.|^2
    float local = 0.f;
    {
#pragma unroll
        for (int k = 0; k < 4; ++k) { int p = pP(tid + (k << 9)); y[k] = mkc(Xr[p], Xi[p]); }
        dit4(y, wexp(tid));
        // s = tid + 512k; kept: s<514 or s>=1537
        local += y[0].r * y[0].r + y[0].i * y[0].i;                    // s = tid < 512 always
        if (tid < 2)  local += y[1].r * y[1].r + y[1].i * y[1].i;      // s in {512,513}
        if (tid >= 1) local += y[3].r * y[3].r + y[3].i * y[3].i;      // s = 1536+tid >= 1537
    }
    local *= (n == 0 || n == 256) ? 1.0f : 2.0f;       // mirror-row weight
#pragma unroll
    for (int off = 32; off >= 1; off >>= 1) local += __shfl_down(local, off);
    if ((tid & 63) == 0) red[tid >> 6] = local;
    __syncthreads();
    if (tid == 0) {
        const float SCALE =
            (float)(1.0 / ((double)MFFT * (double)MFFT * (double)BATCH * (double)T_FRAMES));
        float s = 0.f;
#pragma unroll
        for (int i = 0; i < 8; ++i) s += red[i];
        atomicAdd(out, s * SCALE);
    }
}

extern "C" void kernel_launch(void* const* d_in, const int* in_sizes, int n_in,
                              void* d_out, int out_size, void* d_ws, size_t ws_size,
                              hipStream_t stream) {
    (void)in_sizes; (void)n_in; (void)out_size; (void)ws_size;
    const float* wave   = (const float*)d_in[0];
    const float* window = (const float*)d_in[1];
    const float* ar     = (const float*)d_in[2];
    const float* ai     = (const float*)d_in[3];
    float* out = (float*)d_out;

    char* ws = (char*)d_ws;
    float2* Ht   = (float2*)ws;                          // 4*512*1032*8 = 16,908,288 B
    float2* Afbr = (float2*)(ws + 16908288);             // 7*2048*8    =    114,688 B

    stage1_kernel<<<1036, 256, 0, stream>>>(wave, window, ar, ai, Ht, Afbr, out);
    conv_kernel<<<BATCH * 257, 512, 0, stream>>>(Ht, Afbr, out);
}